// Round 1
// baseline (1175.613 us; speedup 1.0000x reference)
//
#include <hip/hip_runtime.h>
#include <hip/hip_bf16.h>
#include <stdint.h>

// TriangleMultiplication, N=512, C=128, fp32 in/out.
// Strategy: bf16 MFMA everywhere (threshold 0.114 allows it, predicted err ~0.02).
//  k_pack: weights -> bf16, u-layout 4c+{projA,gateA,projB,gateB} + Wgl + Wo
//  k1: LN1 + x@W^T + gate/mask -> a_t,b_t ([i][c][k] bf16) and g=sig(x@Wgl^T) ([cell][c] bf16)
//  k2: tri einsum (per-channel MFMA over k) + fused LN2 + @Wo^T + g-gate + residual

#define NN 512
#define CC 128

typedef __attribute__((ext_vector_type(4))) float f32x4;
typedef __attribute__((ext_vector_type(8))) short bf16x8v;

__device__ __forceinline__ uint16_t f2bf(float f) {
  uint32_t u = __builtin_bit_cast(uint32_t, f);
  uint32_t r = u + 0x7fffu + ((u >> 16) & 1u);
  return (uint16_t)(r >> 16);
}
__device__ __forceinline__ float bf2f(uint16_t h) {
  uint32_t u = ((uint32_t)h) << 16;
  return __builtin_bit_cast(float, u);
}
__device__ __forceinline__ float sigmoidf_(float x) {
  return 1.0f / (1.0f + __expf(-x));
}
__device__ __forceinline__ bf16x8v ldbf8(const uint16_t* p) {
  return *reinterpret_cast<const bf16x8v*>(p);
}
#define MFMA16(a, b, c) __builtin_amdgcn_mfma_f32_16x16x32_bf16((a), (b), (c), 0, 0, 0)

// ---------------- K0: pack weights to bf16, combined layout ----------------
// rows 0..511  : u = 4q+sel ; sel0: Wp[2q], sel1: Wg[2q], sel2: Wp[2q+1], sel3: Wg[2q+1]
// rows 512..639: Wgl[u-512]
// rows 640..767: Wo[u-640]
__global__ __launch_bounds__(128) void k_pack(const float* __restrict__ Wp,
                                              const float* __restrict__ Wg,
                                              const float* __restrict__ Wgl,
                                              const float* __restrict__ Wo,
                                              uint16_t* __restrict__ Wc) {
  int u = blockIdx.x;
  int k = threadIdx.x;
  const float* src;
  if (u < 512) {
    int q = u >> 2, sel = u & 3;
    int row = 2 * q + ((sel >> 1) & 1);
    src = ((sel & 1) ? Wg : Wp) + row * CC;
  } else if (u < 640) {
    src = Wgl + (u - 512) * CC;
  } else {
    src = Wo + (u - 640) * CC;
  }
  Wc[u * CC + k] = f2bf(src[k]);
}

// ---------------- K1: LN1 + projections + gating ----------------
// block: 256 thr (4 waves), 32 cells (same i, k0..k0+31). grid 8192.
__global__ __launch_bounds__(256) void k1(
    const float* __restrict__ pair, const float* __restrict__ mask,
    const float* __restrict__ ln1w, const float* __restrict__ ln1b,
    const uint16_t* __restrict__ Wc,
    uint16_t* __restrict__ a_t, uint16_t* __restrict__ b_t,
    uint16_t* __restrict__ gbuf) {
  __shared__ uint16_t x_s[32][136];  // +8 pad, 16B-aligned rows
  __shared__ float mask_s[32];
  const int t = threadIdx.x;
  const int i = blockIdx.x >> 4;
  const int k0 = (blockIdx.x & 15) << 5;

  // ---- LN1 over 32 rows (8 threads per row) ----
  {
    const int row = t >> 3, seg = t & 7;
    const float* src = pair + (((i << 9) + k0 + row) << 7) + (seg << 4);
    float v[16];
    float s1 = 0.f, s2 = 0.f;
#pragma unroll
    for (int jq = 0; jq < 4; ++jq) {
      f32x4 q = *reinterpret_cast<const f32x4*>(src + 4 * jq);
#pragma unroll
      for (int e = 0; e < 4; ++e) {
        float x = q[e];
        v[jq * 4 + e] = x;
        s1 += x;
        s2 += x * x;
      }
    }
#pragma unroll
    for (int m = 1; m < 8; m <<= 1) {
      s1 += __shfl_xor(s1, m, 8);
      s2 += __shfl_xor(s2, m, 8);
    }
    const float mu = s1 * (1.f / 128.f);
    const float rs = rsqrtf(s2 * (1.f / 128.f) - mu * mu + 1e-5f);
#pragma unroll
    for (int jq = 0; jq < 4; ++jq) {
      ushort4 pk;
#pragma unroll
      for (int e = 0; e < 4; ++e) {
        int c = (seg << 4) + jq * 4 + e;
        float y = (v[jq * 4 + e] - mu) * rs * ln1w[c] + ln1b[c];
        ((uint16_t*)&pk)[e] = f2bf(y);
      }
      *reinterpret_cast<ushort4*>(&x_s[row][(seg << 4) + jq * 4]) = pk;
    }
    if (t < 32) mask_s[t] = mask[(i << 9) + k0 + t];
  }
  __syncthreads();

  const int w = t >> 6, lane = t & 63;
  const int m16 = lane & 15, kg = lane >> 4;

  bf16x8v af[2][4];
#pragma unroll
  for (int mt = 0; mt < 2; ++mt)
#pragma unroll
    for (int ks = 0; ks < 4; ++ks)
      af[mt][ks] =
          *reinterpret_cast<const bf16x8v*>(&x_s[mt * 16 + m16][ks * 32 + kg * 8]);

  // ---- pair-block tiles: wave w handles n-tiles [8w, 8w+8) => channels [32w,32w+32) ----
#pragma unroll
  for (int idx = 0; idx < 8; ++idx) {
    const int nt = 8 * w + idx;
    const int n0 = nt << 4;
    f32x4 acc0 = {0.f, 0.f, 0.f, 0.f};
    f32x4 acc1 = {0.f, 0.f, 0.f, 0.f};
#pragma unroll
    for (int ks = 0; ks < 4; ++ks) {
      bf16x8v bfr = ldbf8(Wc + ((n0 + m16) << 7) + ks * 32 + kg * 8);
      acc0 = MFMA16(af[0][ks], bfr, acc0);
      acc1 = MFMA16(af[1][ks], bfr, acc1);
    }
    const int sel = m16 & 3;
    const int q = (n0 >> 2) + (m16 >> 2);  // channel
#pragma unroll
    for (int mt = 0; mt < 2; ++mt) {
      f32x4 A = mt ? acc1 : acc0;
      ushort4 pk;
#pragma unroll
      for (int r = 0; r < 4; ++r) {
        float gp = __shfl_xor(A[r], 1);  // gate partner lane
        float val = A[r] * mask_s[mt * 16 + kg * 4 + r] * sigmoidf_(gp);
        ((uint16_t*)&pk)[r] = f2bf(val);
      }
      if ((sel & 1) == 0) {
        uint16_t* dst = (sel == 0) ? a_t : b_t;
        const int kpos = k0 + mt * 16 + kg * 4;
        *reinterpret_cast<ushort4*>(&dst[(((i << 7) + q) << 9) + kpos]) = pk;
      }
    }
  }

  // ---- gl tiles: wave w handles 2 tiles -> gbuf[cell][o] (sigmoid applied) ----
#pragma unroll
  for (int idx = 0; idx < 2; ++idx) {
    const int nt = 2 * w + idx;
    const int n0 = 512 + (nt << 4);
    f32x4 acc0 = {0.f, 0.f, 0.f, 0.f};
    f32x4 acc1 = {0.f, 0.f, 0.f, 0.f};
#pragma unroll
    for (int ks = 0; ks < 4; ++ks) {
      bf16x8v bfr = ldbf8(Wc + ((n0 + m16) << 7) + ks * 32 + kg * 8);
      acc0 = MFMA16(af[0][ks], bfr, acc0);
      acc1 = MFMA16(af[1][ks], bfr, acc1);
    }
    const int o = (nt << 4) + m16;
#pragma unroll
    for (int mt = 0; mt < 2; ++mt) {
      f32x4 A = mt ? acc1 : acc0;
#pragma unroll
      for (int r = 0; r < 4; ++r) {
        const int cell2 = k0 + mt * 16 + kg * 4 + r;
        gbuf[(((i << 9) + cell2) << 7) + o] = f2bf(sigmoidf_(A[r]));
      }
    }
  }
}

// ---------------- K2: tri einsum + LN2 + Wo + gate + residual ----------------
// block: 512 thr (8 waves), one 16x16 (i,j) tile, wave w owns channels [16w,16w+16).
// grid 1024 (32x32 tiles), XCD-chunked swizzle.
__global__ __launch_bounds__(512) void k2(
    const float* __restrict__ pair,
    const float* __restrict__ ln2w, const float* __restrict__ ln2b,
    const uint16_t* __restrict__ Wc,
    const uint16_t* __restrict__ a_t, const uint16_t* __restrict__ b_t,
    const uint16_t* __restrict__ gbuf, float* __restrict__ out) {
  __shared__ uint16_t y_s[128 * 136];  // half the cells, bf16 LN2 output (34KB)
  __shared__ float2 stat[256];         // per-cell (mu, rs)
  float2* red = reinterpret_cast<float2*>(y_s);  // reduction scratch (16KB), used before y_s

  const int bidx = blockIdx.x;
  const int nb = ((bidx & 7) << 7) + (bidx >> 3);  // XCD-chunk swizzle (1024 % 8 == 0)
  const int i0 = (nb >> 5) << 4;
  const int j0 = (nb & 31) << 4;
  const int t = threadIdx.x, w = t >> 6, lane = t & 63;
  const int m16 = lane & 15, kg = lane >> 4;
  const int cbase = w << 4;

  const uint16_t* ap = a_t + ((((i0 + m16) << 7) + cbase) << 9) + (kg << 3);
  const uint16_t* bp = b_t + ((((j0 + m16) << 7) + cbase) << 9) + (kg << 3);

  const f32x4 fzero = {0.f, 0.f, 0.f, 0.f};
  f32x4 acc[16];
#pragma unroll
  for (int c = 0; c < 16; ++c) acc[c] = fzero;

  // tri[i,j,c] = sum_k a[i,k,c]*b[j,k,c] : per-channel MFMA, no LDS in main loop
  for (int k = 0; k < 512; k += 32) {
#pragma unroll
    for (int c = 0; c < 16; ++c) {
      bf16x8v A = ldbf8(ap + (c << 9) + k);
      bf16x8v B = ldbf8(bp + (c << 9) + k);
      acc[c] = MFMA16(A, B, acc[c]);
    }
  }

  // ---- LN2 stats: per-lane partials over this wave's 16 channels ----
  {
    float s1[4] = {0.f, 0.f, 0.f, 0.f};
    float s2[4] = {0.f, 0.f, 0.f, 0.f};
#pragma unroll
    for (int c = 0; c < 16; ++c)
#pragma unroll
      for (int r = 0; r < 4; ++r) {
        float xv = acc[c][r];
        s1[r] += xv;
        s2[r] += xv * xv;
      }
#pragma unroll
    for (int r = 0; r < 4; ++r) {
      int cell = ((kg << 2) + r) * 16 + m16;  // iOff*16 + jOff
      red[(w << 8) + cell] = make_float2(s1[r], s2[r]);
    }
  }
  __syncthreads();
  if (t < 256) {
    float a1 = 0.f, a2 = 0.f;
#pragma unroll
    for (int ww = 0; ww < 8; ++ww) {
      float2 p = red[(ww << 8) + t];
      a1 += p.x;
      a2 += p.y;
    }
    float mu = a1 * (1.f / 128.f);
    float rs = rsqrtf(a2 * (1.f / 128.f) - mu * mu + 1e-5f);
    stat[t] = make_float2(mu, rs);
  }
  __syncthreads();

  const uint16_t* WoC = Wc + (640 << 7);

  for (int half = 0; half < 2; ++half) {
    // write LN2 output (bf16) for this half of the cells
    if ((kg >> 1) == half) {
#pragma unroll
      for (int r = 0; r < 4; ++r) {
        const int iOff = (kg << 2) + r;
        const int cellL = ((iOff - (half << 3)) << 4) + m16;
        const float2 st = stat[(iOff << 4) + m16];
#pragma unroll
        for (int jq = 0; jq < 4; ++jq) {
          ushort4 pk;
#pragma unroll
          for (int e = 0; e < 4; ++e) {
            const int c = (jq << 2) + e;
            float y = (acc[c][r] - st.x) * st.y * ln2w[cbase + c] + ln2b[cbase + c];
            ((uint16_t*)&pk)[e] = f2bf(y);
          }
          *reinterpret_cast<ushort4*>(&y_s[cellL * 136 + cbase + (jq << 2)]) = pk;
        }
      }
    }
    __syncthreads();

    // Wo GEMM for this half: wave w -> m-tile (half*8 + w)
    const int mt = (half << 3) + w;
    bf16x8v af2[4];
#pragma unroll
    for (int ks = 0; ks < 4; ++ks)
      af2[ks] = *reinterpret_cast<const bf16x8v*>(
          &y_s[(((mt - (half << 3)) << 4) + m16) * 136 + ks * 32 + (kg << 3)]);
    const int i = i0 + mt;
#pragma unroll
    for (int nt = 0; nt < 8; ++nt) {
      f32x4 a2 = fzero;
#pragma unroll
      for (int ks = 0; ks < 4; ++ks) {
        bf16x8v bw = ldbf8(WoC + (((nt << 4) + m16) << 7) + ks * 32 + (kg << 3));
        a2 = MFMA16(af2[ks], bw, a2);
      }
      const int o = (nt << 4) + m16;
#pragma unroll
      for (int r = 0; r < 4; ++r) {
        const int j = j0 + (kg << 2) + r;
        const int off = (((i << 9) + j) << 7) + o;
        out[off] = pair[off] + a2[r] * bf2f(gbuf[off]);
      }
    }
    __syncthreads();
  }
}

extern "C" void kernel_launch(void* const* d_in, const int* in_sizes, int n_in,
                              void* d_out, int out_size, void* d_ws, size_t ws_size,
                              hipStream_t stream) {
  const float* pair = (const float*)d_in[0];
  const float* mask = (const float*)d_in[1];
  const float* ln1w = (const float*)d_in[2];
  const float* ln1b = (const float*)d_in[3];
  const float* Wp = (const float*)d_in[4];
  const float* Wg = (const float*)d_in[5];
  const float* ln2w = (const float*)d_in[6];
  const float* ln2b = (const float*)d_in[7];
  const float* Wo = (const float*)d_in[8];
  const float* Wgl = (const float*)d_in[9];

  uint8_t* ws = (uint8_t*)d_ws;
  // layout: Wc (192KB, padded to 256KB) | a_t 64MB | b_t 64MB | g 64MB  (total ~192.25MB)
  uint16_t* Wc = (uint16_t*)(ws);
  uint16_t* a_t = (uint16_t*)(ws + (1 << 18));
  uint16_t* b_t = (uint16_t*)(ws + (1 << 18) + (1 << 26));
  uint16_t* gb = (uint16_t*)(ws + (1 << 18) + (2u << 26));

  hipLaunchKernelGGL(k_pack, dim3(768), dim3(128), 0, stream, Wp, Wg, Wgl, Wo, Wc);
  hipLaunchKernelGGL(k1, dim3(8192), dim3(256), 0, stream, pair, mask, ln1w, ln1b,
                     Wc, a_t, b_t, gb);
  hipLaunchKernelGGL(k2, dim3(1024), dim3(512), 0, stream, pair, ln2w, ln2b, Wc,
                     a_t, b_t, gb, (float*)d_out);
}

// Round 3
// 652.346 us; speedup vs baseline: 1.8021x; 1.8021x over previous
//
#include <hip/hip_runtime.h>
#include <hip/hip_bf16.h>
#include <stdint.h>

// TriangleMultiplication, N=512, C=128, fp32 in/out.
//  k_pack: weights -> bf16 (u-layout 4c+{pA,gA,pB,gB} | Wgl | Wo)
//  k1: LN1 + x@W^T + gate/mask -> a_t,b_t ([i][c][k] bf16), g=sig(x@Wgl^T) ([i][j][c] bf16)
//  k2a: per-channel NT-GEMM tri[c][i][j] = A_c B_c^T (bf16), channel-per-XCD swizzle
//  k2b: gather tri + LN2 + @Wo^T + g-gate + residual
//  (old fused k2 kept as fallback if ws_size < 256.25 MB)

#define NN 512
#define CC 128

typedef __attribute__((ext_vector_type(4))) float f32x4;
typedef __attribute__((ext_vector_type(8))) short bf16x8v;

__device__ __forceinline__ uint16_t f2bf(float f) {
  uint32_t u = __builtin_bit_cast(uint32_t, f);
  uint32_t r = u + 0x7fffu + ((u >> 16) & 1u);
  return (uint16_t)(r >> 16);
}
__device__ __forceinline__ float bf2f(uint16_t h) {
  uint32_t u = ((uint32_t)h) << 16;
  return __builtin_bit_cast(float, u);
}
__device__ __forceinline__ float sigmoidf_(float x) {
  return 1.0f / (1.0f + __expf(-x));
}
__device__ __forceinline__ bf16x8v ldbf8(const uint16_t* p) {
  return *reinterpret_cast<const bf16x8v*>(p);
}
#define MFMA16(a, b, c) __builtin_amdgcn_mfma_f32_16x16x32_bf16((a), (b), (c), 0, 0, 0)

// ---------------- K0: pack weights to bf16 ----------------
__global__ __launch_bounds__(128) void k_pack(const float* __restrict__ Wp,
                                              const float* __restrict__ Wg,
                                              const float* __restrict__ Wgl,
                                              const float* __restrict__ Wo,
                                              uint16_t* __restrict__ Wc) {
  int u = blockIdx.x;
  int k = threadIdx.x;
  const float* src;
  if (u < 512) {
    int q = u >> 2, sel = u & 3;
    int row = 2 * q + ((sel >> 1) & 1);
    src = ((sel & 1) ? Wg : Wp) + row * CC;
  } else if (u < 640) {
    src = Wgl + (u - 512) * CC;
  } else {
    src = Wo + (u - 640) * CC;
  }
  Wc[u * CC + k] = f2bf(src[k]);
}

// ---------------- K1: LN1 + projections + gating ----------------
__global__ __launch_bounds__(256) void k1(
    const float* __restrict__ pair, const float* __restrict__ mask,
    const float* __restrict__ ln1w, const float* __restrict__ ln1b,
    const uint16_t* __restrict__ Wc,
    uint16_t* __restrict__ a_t, uint16_t* __restrict__ b_t,
    uint16_t* __restrict__ gbuf) {
  __shared__ uint16_t x_s[32][136];
  __shared__ float mask_s[32];
  const int t = threadIdx.x;
  const int i = blockIdx.x >> 4;
  const int k0 = (blockIdx.x & 15) << 5;

  {
    const int row = t >> 3, seg = t & 7;
    const float* src = pair + (((i << 9) + k0 + row) << 7) + (seg << 4);
    float v[16];
    float s1 = 0.f, s2 = 0.f;
#pragma unroll
    for (int jq = 0; jq < 4; ++jq) {
      f32x4 q = *reinterpret_cast<const f32x4*>(src + 4 * jq);
#pragma unroll
      for (int e = 0; e < 4; ++e) {
        float x = q[e];
        v[jq * 4 + e] = x;
        s1 += x;
        s2 += x * x;
      }
    }
#pragma unroll
    for (int m = 1; m < 8; m <<= 1) {
      s1 += __shfl_xor(s1, m, 8);
      s2 += __shfl_xor(s2, m, 8);
    }
    const float mu = s1 * (1.f / 128.f);
    const float rs = rsqrtf(s2 * (1.f / 128.f) - mu * mu + 1e-5f);
#pragma unroll
    for (int jq = 0; jq < 4; ++jq) {
      ushort4 pk;
#pragma unroll
      for (int e = 0; e < 4; ++e) {
        int c = (seg << 4) + jq * 4 + e;
        float y = (v[jq * 4 + e] - mu) * rs * ln1w[c] + ln1b[c];
        ((uint16_t*)&pk)[e] = f2bf(y);
      }
      *reinterpret_cast<ushort4*>(&x_s[row][(seg << 4) + jq * 4]) = pk;
    }
    if (t < 32) mask_s[t] = mask[(i << 9) + k0 + t];
  }
  __syncthreads();

  const int w = t >> 6, lane = t & 63;
  const int m16 = lane & 15, kg = lane >> 4;

  bf16x8v af[2][4];
#pragma unroll
  for (int mt = 0; mt < 2; ++mt)
#pragma unroll
    for (int ks = 0; ks < 4; ++ks)
      af[mt][ks] =
          *reinterpret_cast<const bf16x8v*>(&x_s[mt * 16 + m16][ks * 32 + kg * 8]);

#pragma unroll
  for (int idx = 0; idx < 8; ++idx) {
    const int nt = 8 * w + idx;
    const int n0 = nt << 4;
    f32x4 acc0 = {0.f, 0.f, 0.f, 0.f};
    f32x4 acc1 = {0.f, 0.f, 0.f, 0.f};
#pragma unroll
    for (int ks = 0; ks < 4; ++ks) {
      bf16x8v bfr = ldbf8(Wc + ((n0 + m16) << 7) + ks * 32 + kg * 8);
      acc0 = MFMA16(af[0][ks], bfr, acc0);
      acc1 = MFMA16(af[1][ks], bfr, acc1);
    }
    const int sel = m16 & 3;
    const int q = (n0 >> 2) + (m16 >> 2);
#pragma unroll
    for (int mt = 0; mt < 2; ++mt) {
      f32x4 A = mt ? acc1 : acc0;
      ushort4 pk;
#pragma unroll
      for (int r = 0; r < 4; ++r) {
        float gp = __shfl_xor(A[r], 1);
        float val = A[r] * mask_s[mt * 16 + kg * 4 + r] * sigmoidf_(gp);
        ((uint16_t*)&pk)[r] = f2bf(val);
      }
      if ((sel & 1) == 0) {
        uint16_t* dst = (sel == 0) ? a_t : b_t;
        const int kpos = k0 + mt * 16 + kg * 4;
        *reinterpret_cast<ushort4*>(&dst[(((i << 7) + q) << 9) + kpos]) = pk;
      }
    }
  }

#pragma unroll
  for (int idx = 0; idx < 2; ++idx) {
    const int nt = 2 * w + idx;
    const int n0 = 512 + (nt << 4);
    f32x4 acc0 = {0.f, 0.f, 0.f, 0.f};
    f32x4 acc1 = {0.f, 0.f, 0.f, 0.f};
#pragma unroll
    for (int ks = 0; ks < 4; ++ks) {
      bf16x8v bfr = ldbf8(Wc + ((n0 + m16) << 7) + ks * 32 + kg * 8);
      acc0 = MFMA16(af[0][ks], bfr, acc0);
      acc1 = MFMA16(af[1][ks], bfr, acc1);
    }
    const int o = (nt << 4) + m16;
#pragma unroll
    for (int mt = 0; mt < 2; ++mt) {
      f32x4 A = mt ? acc1 : acc0;
#pragma unroll
      for (int r = 0; r < 4; ++r) {
        const int cell2 = k0 + mt * 16 + kg * 4 + r;
        gbuf[(((i << 9) + cell2) << 7) + o] = f2bf(sigmoidf_(A[r]));
      }
    }
  }
}

// ---------------- K2a: per-channel NT-GEMM, tri[c][i][j] bf16 ----------------
// grid 2048 = 128 channels x 16 tiles(128x128); swizzle: channel-chunk per XCD.
__global__ __launch_bounds__(256) void k2a(const uint16_t* __restrict__ a_t,
                                           const uint16_t* __restrict__ b_t,
                                           uint16_t* __restrict__ tri) {
  const int swz = ((blockIdx.x & 7) << 8) | (blockIdx.x >> 3);
  const int c = swz >> 4, tl = swz & 15;
  const int i0 = (tl >> 2) << 7, j0 = (tl & 3) << 7;
  const int t = threadIdx.x, w = t >> 6, lane = t & 63;
  const int m16 = lane & 15, kg = lane >> 4;
  const int ib = i0 + ((w >> 1) << 6), jb = j0 + ((w & 1) << 6);
  const uint16_t* ap = a_t + ((size_t)(ib + m16) << 16) + (c << 9) + (kg << 3);
  const uint16_t* bp = b_t + ((size_t)(jb + m16) << 16) + (c << 9) + (kg << 3);

  const f32x4 fz = {0.f, 0.f, 0.f, 0.f};
  f32x4 acc[4][4];
#pragma unroll
  for (int mt = 0; mt < 4; ++mt)
#pragma unroll
    for (int nt = 0; nt < 4; ++nt) acc[mt][nt] = fz;

  for (int k = 0; k < 512; k += 32) {
    bf16x8v af[4], bf[4];
#pragma unroll
    for (int mt = 0; mt < 4; ++mt) af[mt] = ldbf8(ap + (mt << 20) + k);
#pragma unroll
    for (int nt = 0; nt < 4; ++nt) bf[nt] = ldbf8(bp + (nt << 20) + k);
#pragma unroll
    for (int mt = 0; mt < 4; ++mt)
#pragma unroll
      for (int nt = 0; nt < 4; ++nt)
        acc[mt][nt] = MFMA16(af[mt], bf[nt], acc[mt][nt]);
  }

  uint16_t* cp = tri + ((size_t)c << 18);
#pragma unroll
  for (int mt = 0; mt < 4; ++mt)
#pragma unroll
    for (int r = 0; r < 4; ++r) {
      const int irow = ib + (mt << 4) + (kg << 2) + r;
#pragma unroll
      for (int nt = 0; nt < 4; ++nt)
        cp[(irow << 9) + jb + (nt << 4) + m16] = f2bf(acc[mt][nt][r]);
    }
}

// ---------------- K2b: LN2 + Wo + gate + residual ----------------
// grid 1024 (16x16 cell tiles), 512 thr (8 waves).
__global__ __launch_bounds__(512) void k2b(
    const float* __restrict__ pair,
    const float* __restrict__ ln2w, const float* __restrict__ ln2b,
    const uint16_t* __restrict__ Wc,
    const uint16_t* __restrict__ tri,
    const uint16_t* __restrict__ gbuf, float* __restrict__ out) {
  __shared__ uint16_t y_s[256][136];
  __shared__ float2 red[512];
  __shared__ float2 stat[256];
  __shared__ float wln[128], bln[128];

  const int t = threadIdx.x;
  const int i0 = (blockIdx.x >> 5) << 4;
  const int j0 = (blockIdx.x & 31) << 4;
  const int cell = t & 255, ch = t >> 8;
  const int il = cell >> 4, jl = cell & 15;

  if (t < 128) {
    wln[t] = ln2w[t];
    bln[t] = ln2b[t];
  }

  const uint16_t* tp =
      tri + ((size_t)(ch << 6) << 18) + ((i0 + il) << 9) + j0 + jl;
  unsigned short v[64];
  float s1 = 0.f, s2 = 0.f;
#pragma unroll
  for (int cc = 0; cc < 64; ++cc) {
    unsigned short u = tp[(size_t)cc << 18];
    v[cc] = u;
    float f = bf2f(u);
    s1 += f;
    s2 += f * f;
  }
  red[t] = make_float2(s1, s2);
  __syncthreads();
  if (t < 256) {
    float2 p0 = red[t], p1 = red[t + 256];
    float a1 = p0.x + p1.x, a2 = p0.y + p1.y;
    float mu = a1 * (1.f / 128.f);
    float rs = rsqrtf(a2 * (1.f / 128.f) - mu * mu + 1e-5f);
    stat[t] = make_float2(mu, rs);
  }
  __syncthreads();

  {
    const float2 st = stat[cell];
#pragma unroll
    for (int cq = 0; cq < 16; ++cq) {
      ushort4 pk;
#pragma unroll
      for (int e = 0; e < 4; ++e) {
        const int c = (ch << 6) + (cq << 2) + e;
        float y = (bf2f(v[cq * 4 + e]) - st.x) * st.y * wln[c] + bln[c];
        ((unsigned short*)&pk)[e] = f2bf(y);
      }
      *reinterpret_cast<ushort4*>(&y_s[cell][(ch << 6) + (cq << 2)]) = pk;
    }
  }
  __syncthreads();

  const int w = t >> 6, lane = t & 63, m16 = lane & 15, kg = lane >> 4;
  const uint16_t* WoC = Wc + (640 << 7);

  bf16x8v af[2][4];
#pragma unroll
  for (int h = 0; h < 2; ++h) {
    const int mt = w + (h << 3);
#pragma unroll
    for (int ks = 0; ks < 4; ++ks)
      af[h][ks] = *reinterpret_cast<const bf16x8v*>(
          &y_s[(mt << 4) + m16][(ks << 5) + (kg << 3)]);
  }

  const f32x4 fz = {0.f, 0.f, 0.f, 0.f};
#pragma unroll
  for (int nt = 0; nt < 8; ++nt) {
    bf16x8v bw[4];
#pragma unroll
    for (int ks = 0; ks < 4; ++ks)
      bw[ks] = ldbf8(WoC + (((nt << 4) + m16) << 7) + (ks << 5) + (kg << 3));
    f32x4 acc0 = fz, acc1 = fz;
#pragma unroll
    for (int ks = 0; ks < 4; ++ks) {
      acc0 = MFMA16(af[0][ks], bw[ks], acc0);
      acc1 = MFMA16(af[1][ks], bw[ks], acc1);
    }
    const int o = (nt << 4) + m16;
#pragma unroll
    for (int h = 0; h < 2; ++h) {
      const int mt = w + (h << 3);
      f32x4 A = h ? acc1 : acc0;
#pragma unroll
      for (int r = 0; r < 4; ++r) {
        const int off = ((((i0 + mt) << 9) + j0 + (kg << 2) + r) << 7) + o;
        out[off] = pair[off] + A[r] * bf2f(gbuf[off]);
      }
    }
  }
}

// ---------------- old fused K2 (fallback if ws too small) ----------------
__global__ __launch_bounds__(512) void k2(
    const float* __restrict__ pair,
    const float* __restrict__ ln2w, const float* __restrict__ ln2b,
    const uint16_t* __restrict__ Wc,
    const uint16_t* __restrict__ a_t, const uint16_t* __restrict__ b_t,
    const uint16_t* __restrict__ gbuf, float* __restrict__ out) {
  __shared__ uint16_t y_s[128 * 136];
  __shared__ float2 stat[256];
  float2* red = reinterpret_cast<float2*>(y_s);

  const int bidx = blockIdx.x;
  const int nb = ((bidx & 7) << 7) + (bidx >> 3);
  const int i0 = (nb >> 5) << 4;
  const int j0 = (nb & 31) << 4;
  const int t = threadIdx.x, w = t >> 6, lane = t & 63;
  const int m16 = lane & 15, kg = lane >> 4;
  const int cbase = w << 4;

  const uint16_t* ap = a_t + ((((i0 + m16) << 7) + cbase) << 9) + (kg << 3);
  const uint16_t* bp = b_t + ((((j0 + m16) << 7) + cbase) << 9) + (kg << 3);

  const f32x4 fzero = {0.f, 0.f, 0.f, 0.f};
  f32x4 acc[16];
#pragma unroll
  for (int c = 0; c < 16; ++c) acc[c] = fzero;

  for (int k = 0; k < 512; k += 32) {
#pragma unroll
    for (int c = 0; c < 16; ++c) {
      bf16x8v A = ldbf8(ap + (c << 9) + k);
      bf16x8v B = ldbf8(bp + (c << 9) + k);
      acc[c] = MFMA16(A, B, acc[c]);
    }
  }

  {
    float s1[4] = {0.f, 0.f, 0.f, 0.f};
    float s2[4] = {0.f, 0.f, 0.f, 0.f};
#pragma unroll
    for (int c = 0; c < 16; ++c)
#pragma unroll
      for (int r = 0; r < 4; ++r) {
        float xv = acc[c][r];
        s1[r] += xv;
        s2[r] += xv * xv;
      }
#pragma unroll
    for (int r = 0; r < 4; ++r) {
      int cell = ((kg << 2) + r) * 16 + m16;
      red[(w << 8) + cell] = make_float2(s1[r], s2[r]);
    }
  }
  __syncthreads();
  if (t < 256) {
    float a1 = 0.f, a2 = 0.f;
#pragma unroll
    for (int ww = 0; ww < 8; ++ww) {
      float2 p = red[(ww << 8) + t];
      a1 += p.x;
      a2 += p.y;
    }
    float mu = a1 * (1.f / 128.f);
    float rs = rsqrtf(a2 * (1.f / 128.f) - mu * mu + 1e-5f);
    stat[t] = make_float2(mu, rs);
  }
  __syncthreads();

  const uint16_t* WoC = Wc + (640 << 7);

  for (int half = 0; half < 2; ++half) {
    if ((kg >> 1) == half) {
#pragma unroll
      for (int r = 0; r < 4; ++r) {
        const int iOff = (kg << 2) + r;
        const int cellL = ((iOff - (half << 3)) << 4) + m16;
        const float2 st = stat[(iOff << 4) + m16];
#pragma unroll
        for (int jq = 0; jq < 4; ++jq) {
          ushort4 pk;
#pragma unroll
          for (int e = 0; e < 4; ++e) {
            const int c = (jq << 2) + e;
            float y = (acc[c][r] - st.x) * st.y * ln2w[cbase + c] + ln2b[cbase + c];
            ((uint16_t*)&pk)[e] = f2bf(y);
          }
          *reinterpret_cast<ushort4*>(&y_s[cellL * 136 + cbase + (jq << 2)]) = pk;
        }
      }
    }
    __syncthreads();

    const int mt = (half << 3) + w;
    bf16x8v af2[4];
#pragma unroll
    for (int ks = 0; ks < 4; ++ks)
      af2[ks] = *reinterpret_cast<const bf16x8v*>(
          &y_s[(((mt - (half << 3)) << 4) + m16) * 136 + ks * 32 + (kg << 3)]);
    const int i = i0 + mt;
#pragma unroll
    for (int nt = 0; nt < 8; ++nt) {
      f32x4 a2 = fzero;
#pragma unroll
      for (int ks = 0; ks < 4; ++ks) {
        bf16x8v bw = ldbf8(WoC + (((nt << 4) + m16) << 7) + ks * 32 + (kg << 3));
        a2 = MFMA16(af2[ks], bw, a2);
      }
      const int o = (nt << 4) + m16;
#pragma unroll
      for (int r = 0; r < 4; ++r) {
        const int j = j0 + (kg << 2) + r;
        const int off = (((i << 9) + j) << 7) + o;
        out[off] = pair[off] + a2[r] * bf2f(gbuf[off]);
      }
    }
    __syncthreads();
  }
}

extern "C" void kernel_launch(void* const* d_in, const int* in_sizes, int n_in,
                              void* d_out, int out_size, void* d_ws, size_t ws_size,
                              hipStream_t stream) {
  const float* pair = (const float*)d_in[0];
  const float* mask = (const float*)d_in[1];
  const float* ln1w = (const float*)d_in[2];
  const float* ln1b = (const float*)d_in[3];
  const float* Wp = (const float*)d_in[4];
  const float* Wg = (const float*)d_in[5];
  const float* ln2w = (const float*)d_in[6];
  const float* ln2b = (const float*)d_in[7];
  const float* Wo = (const float*)d_in[8];
  const float* Wgl = (const float*)d_in[9];

  uint8_t* ws = (uint8_t*)d_ws;
  // layout: Wc 256KB | a_t 64MB | b_t 64MB | gbuf 64MB | tri 64MB
  uint16_t* Wc = (uint16_t*)(ws);
  uint16_t* a_t = (uint16_t*)(ws + (1 << 18));
  uint16_t* b_t = (uint16_t*)(ws + (1 << 18) + (1ull << 26));
  uint16_t* gb = (uint16_t*)(ws + (1 << 18) + (2ull << 26));
  uint16_t* tri = (uint16_t*)(ws + (1 << 18) + (3ull << 26));
  const size_t NEED = (1 << 18) + (4ull << 26);

  hipLaunchKernelGGL(k_pack, dim3(768), dim3(128), 0, stream, Wp, Wg, Wgl, Wo, Wc);
  hipLaunchKernelGGL(k1, dim3(8192), dim3(256), 0, stream, pair, mask, ln1w, ln1b,
                     Wc, a_t, b_t, gb);
  if (ws_size >= NEED) {
    hipLaunchKernelGGL(k2a, dim3(2048), dim3(256), 0, stream, a_t, b_t, tri);
    hipLaunchKernelGGL(k2b, dim3(1024), dim3(512), 0, stream, pair, ln2w, ln2b,
                       Wc, tri, gb, (float*)d_out);
  } else {
    hipLaunchKernelGGL(k2, dim3(1024), dim3(512), 0, stream, pair, ln2w, ln2b, Wc,
                       a_t, b_t, gb, (float*)d_out);
  }
}

// Round 4
// 608.079 us; speedup vs baseline: 1.9333x; 1.0728x over previous
//
#include <hip/hip_runtime.h>
#include <hip/hip_bf16.h>
#include <stdint.h>

// TriangleMultiplication, N=512, C=128, fp32 in/out. bf16-MFMA pipeline:
//  k_pack: Wc bf16: tiles 2m=Wp[16m..16m+16), 2m+1=Wg[16m..) | Wgl@512 | Wo@640
//  k1: LN1 + proj/gate (lane-local pairing, no shfl) -> a_t,b_t [i][c][k];
//      gl -> gbuf2 [i][o][j] (vector stores)
//  k2a: per-channel 128x128 NT-GEMM tiles, LDS double-buffer via global_load_lds,
//       XOR-swizzled source chunks, channel-per-XCD swizzle
//  k2b: 8x32 cell tiles: vectorized tri gather + LN2 + Wo MFMA + gate + residual

#define NN 512
#define CC 128

typedef __attribute__((ext_vector_type(4))) float f32x4;
typedef __attribute__((ext_vector_type(8))) short bf16x8v;

__device__ __forceinline__ uint16_t f2bf(float f) {
  uint32_t u = __builtin_bit_cast(uint32_t, f);
  uint32_t r = u + 0x7fffu + ((u >> 16) & 1u);
  return (uint16_t)(r >> 16);
}
__device__ __forceinline__ float bf2f(uint16_t h) {
  uint32_t u = ((uint32_t)h) << 16;
  return __builtin_bit_cast(float, u);
}
__device__ __forceinline__ float sigmoidf_(float x) {
  return 1.0f / (1.0f + __expf(-x));
}
__device__ __forceinline__ bf16x8v ldbf8(const uint16_t* p) {
  return *reinterpret_cast<const bf16x8v*>(p);
}
#define MFMA16(a, b, c) __builtin_amdgcn_mfma_f32_16x16x32_bf16((a), (b), (c), 0, 0, 0)

// ---------------- K0: pack weights to bf16 ----------------
// rows 0..511: tile tau=u>>4, r=u&15, m=tau>>1; even tau: Wp[16m+r], odd: Wg[16m+r]
// rows 512..639: Wgl ; rows 640..767: Wo
__global__ __launch_bounds__(128) void k_pack(const float* __restrict__ Wp,
                                              const float* __restrict__ Wg,
                                              const float* __restrict__ Wgl,
                                              const float* __restrict__ Wo,
                                              uint16_t* __restrict__ Wc) {
  int u = blockIdx.x;
  int k = threadIdx.x;
  const float* src;
  if (u < 512) {
    int tau = u >> 4, r = u & 15, m = tau >> 1;
    src = ((tau & 1) ? Wg : Wp) + (16 * m + r) * CC;
  } else if (u < 640) {
    src = Wgl + (u - 512) * CC;
  } else {
    src = Wo + (u - 640) * CC;
  }
  Wc[u * CC + k] = f2bf(src[k]);
}

// ---------------- K1: LN1 + projections + gating ----------------
// block 256 thr (4 waves), 32 cells (row i, k0..k0+31). grid 8192.
__global__ __launch_bounds__(256) void k1(
    const float* __restrict__ pair, const float* __restrict__ mask,
    const float* __restrict__ ln1w, const float* __restrict__ ln1b,
    const uint16_t* __restrict__ Wc,
    uint16_t* __restrict__ a_t, uint16_t* __restrict__ b_t,
    uint16_t* __restrict__ gbuf2) {
  __shared__ uint16_t x_s[32][136];
  __shared__ float mask_s[32];
  const int t = threadIdx.x;
  const int i = blockIdx.x >> 4;
  const int k0 = (blockIdx.x & 15) << 5;

  // ---- LN1 over 32 rows (8 threads per row) ----
  {
    const int row = t >> 3, seg = t & 7;
    const float* src = pair + (((i << 9) + k0 + row) << 7) + (seg << 4);
    float v[16];
    float s1 = 0.f, s2 = 0.f;
#pragma unroll
    for (int jq = 0; jq < 4; ++jq) {
      f32x4 q = *reinterpret_cast<const f32x4*>(src + 4 * jq);
#pragma unroll
      for (int e = 0; e < 4; ++e) {
        float x = q[e];
        v[jq * 4 + e] = x;
        s1 += x;
        s2 += x * x;
      }
    }
#pragma unroll
    for (int m = 1; m < 8; m <<= 1) {
      s1 += __shfl_xor(s1, m, 8);
      s2 += __shfl_xor(s2, m, 8);
    }
    const float mu = s1 * (1.f / 128.f);
    const float rs = rsqrtf(s2 * (1.f / 128.f) - mu * mu + 1e-5f);
#pragma unroll
    for (int jq = 0; jq < 4; ++jq) {
      ushort4 pk;
#pragma unroll
      for (int e = 0; e < 4; ++e) {
        int c = (seg << 4) + jq * 4 + e;
        float y = (v[jq * 4 + e] - mu) * rs * ln1w[c] + ln1b[c];
        ((uint16_t*)&pk)[e] = f2bf(y);
      }
      *reinterpret_cast<ushort4*>(&x_s[row][(seg << 4) + jq * 4]) = pk;
    }
    if (t < 32) mask_s[t] = mask[(i << 9) + k0 + t];
  }
  __syncthreads();

  const int w = t >> 6, lane = t & 63;
  const int m16 = lane & 15, kg = lane >> 4;
  const f32x4 fz = {0.f, 0.f, 0.f, 0.f};

  bf16x8v af[2][4];
#pragma unroll
  for (int mt = 0; mt < 2; ++mt)
#pragma unroll
    for (int ks = 0; ks < 4; ++ks)
      af[mt][ks] =
          *reinterpret_cast<const bf16x8v*>(&x_s[mt * 16 + m16][ks * 32 + kg * 8]);

  // ---- proj/gate pairs: wave w owns m = 4w..4w+3 (lane-local gating) ----
#pragma unroll
  for (int idx = 0; idx < 4; ++idx) {
    const int m = 4 * w + idx;
    const uint16_t* wp = Wc + (((2 * m) * 16 + m16) << 7) + kg * 8;
    const uint16_t* wg = Wc + (((2 * m + 1) * 16 + m16) << 7) + kg * 8;
    f32x4 ap0 = fz, ap1 = fz, ag0 = fz, ag1 = fz;
#pragma unroll
    for (int ks = 0; ks < 4; ++ks) {
      bf16x8v bp = ldbf8(wp + ks * 32);
      bf16x8v bg = ldbf8(wg + ks * 32);
      ap0 = MFMA16(af[0][ks], bp, ap0);
      ap1 = MFMA16(af[1][ks], bp, ap1);
      ag0 = MFMA16(af[0][ks], bg, ag0);
      ag1 = MFMA16(af[1][ks], bg, ag1);
    }
    const int q = 8 * m + (m16 >> 1);  // output channel
    uint16_t* dst = (m16 & 1) ? b_t : a_t;
    uint16_t* base = dst + (((i << 7) + q) << 9) + k0;
#pragma unroll
    for (int mt = 0; mt < 2; ++mt) {
      f32x4 P = mt ? ap1 : ap0;
      f32x4 G = mt ? ag1 : ag0;
      ushort4 pk;
#pragma unroll
      for (int r = 0; r < 4; ++r) {
        float val = P[r] * mask_s[mt * 16 + kg * 4 + r] * sigmoidf_(G[r]);
        ((uint16_t*)&pk)[r] = f2bf(val);
      }
      *reinterpret_cast<ushort4*>(base + mt * 16 + kg * 4) = pk;
    }
  }

  // ---- gl tiles -> gbuf2[i][o][j], vector stores ----
#pragma unroll
  for (int idx = 0; idx < 2; ++idx) {
    const int nt = 2 * w + idx;
    const int n0 = 512 + (nt << 4);
    f32x4 a0 = fz, a1 = fz;
#pragma unroll
    for (int ks = 0; ks < 4; ++ks) {
      bf16x8v bfr = ldbf8(Wc + ((n0 + m16) << 7) + ks * 32 + kg * 8);
      a0 = MFMA16(af[0][ks], bfr, a0);
      a1 = MFMA16(af[1][ks], bfr, a1);
    }
    const int o = (nt << 4) + m16;
    uint16_t* gb = gbuf2 + (((i << 7) + o) << 9) + k0;
#pragma unroll
    for (int mt = 0; mt < 2; ++mt) {
      f32x4 A = mt ? a1 : a0;
      ushort4 pk;
#pragma unroll
      for (int r = 0; r < 4; ++r) ((uint16_t*)&pk)[r] = f2bf(sigmoidf_(A[r]));
      *reinterpret_cast<ushort4*>(gb + mt * 16 + kg * 4) = pk;
    }
  }
}

// ---------------- K2a: per-channel NT-GEMM via LDS double-buffer ----------------
// grid 2048 = 128 ch x 16 tiles(128x128), 256 thr (4 waves, 64x64 quadrants).
// LDS: A,B tiles [128][64] bf16, 2 buffers = 64 KB. Source-chunk XOR swizzle
// (g = (lane&7)^(lane>>3)) with linear global_load_lds dest; ds_read applies
// the same XOR -> 2-way (free) bank pattern.
__global__ __launch_bounds__(256, 2) void k2a(const uint16_t* __restrict__ a_t,
                                              const uint16_t* __restrict__ b_t,
                                              uint16_t* __restrict__ tri) {
  __shared__ uint16_t ldsAB[32768];  // [A buf0|A buf1|B buf0|B buf1] x 8192
  const int swz = ((blockIdx.x & 7) << 8) | (blockIdx.x >> 3);
  const int c = swz >> 4, tl = swz & 15;
  const int i0 = (tl >> 2) << 7, j0 = (tl & 3) << 7;
  const int t = threadIdx.x, w = t >> 6, lane = t & 63;
  const int m16 = lane & 15, kg = lane >> 4;
  const int g = (lane & 7) ^ (lane >> 3);  // swizzled source chunk

  const uint16_t* aSrc =
      a_t + ((size_t)((i0 + (w << 5) + (lane >> 3)) << 7) + c) * 512 + (g << 3);
  const uint16_t* bSrc =
      b_t + ((size_t)((j0 + (w << 5) + (lane >> 3)) << 7) + c) * 512 + (g << 3);

#define STAGE(dstbuf, kt)                                                        \
  {                                                                              \
    _Pragma("unroll") for (int q = 0; q < 4; ++q) {                              \
      __builtin_amdgcn_global_load_lds(                                          \
          (const __attribute__((address_space(1))) void*)(aSrc +                 \
                                                          ((size_t)q << 19) +    \
                                                          ((kt) << 6)),          \
          (__attribute__((address_space(3))) void*)(ldsAB + (dstbuf)*8192 +      \
                                                    (w << 11) + (q << 9)),       \
          16, 0, 0);                                                             \
      __builtin_amdgcn_global_load_lds(                                          \
          (const __attribute__((address_space(1))) void*)(bSrc +                 \
                                                          ((size_t)q << 19) +    \
                                                          ((kt) << 6)),          \
          (__attribute__((address_space(3))) void*)(ldsAB + 16384 +              \
                                                    (dstbuf)*8192 + (w << 11) +  \
                                                    (q << 9)),                   \
          16, 0, 0);                                                             \
    }                                                                            \
  }

  const int wi = (w >> 1) << 6, wj = (w & 1) << 6;
  const f32x4 fz = {0.f, 0.f, 0.f, 0.f};
  f32x4 acc[4][4];
#pragma unroll
  for (int mt = 0; mt < 4; ++mt)
#pragma unroll
    for (int nt = 0; nt < 4; ++nt) acc[mt][nt] = fz;

  STAGE(0, 0);
  __syncthreads();

  for (int kt = 0; kt < 8; ++kt) {
    const int cur = kt & 1;
    if (kt < 7) STAGE(cur ^ 1, kt + 1);
    const uint16_t* lA = ldsAB + cur * 8192;
    const uint16_t* lB = ldsAB + 16384 + cur * 8192;
    bf16x8v afr[4][2], bfr[4][2];
#pragma unroll
    for (int mt = 0; mt < 4; ++mt) {
      const int R = wi + (mt << 4) + m16;
      const int rb = R << 6, rx = R & 7;
#pragma unroll
      for (int ks = 0; ks < 2; ++ks)
        afr[mt][ks] = *reinterpret_cast<const bf16x8v*>(
            &lA[rb + ((((ks << 2) + kg) ^ rx) << 3)]);
    }
#pragma unroll
    for (int nt = 0; nt < 4; ++nt) {
      const int R = wj + (nt << 4) + m16;
      const int rb = R << 6, rx = R & 7;
#pragma unroll
      for (int ks = 0; ks < 2; ++ks)
        bfr[nt][ks] = *reinterpret_cast<const bf16x8v*>(
            &lB[rb + ((((ks << 2) + kg) ^ rx) << 3)]);
    }
#pragma unroll
    for (int mt = 0; mt < 4; ++mt)
#pragma unroll
      for (int nt = 0; nt < 4; ++nt) {
        acc[mt][nt] = MFMA16(afr[mt][0], bfr[nt][0], acc[mt][nt]);
        acc[mt][nt] = MFMA16(afr[mt][1], bfr[nt][1], acc[mt][nt]);
      }
    __syncthreads();  // drains vmcnt (next-buf staging) + protects buffer reuse
  }
#undef STAGE

  uint16_t* cp = tri + ((size_t)c << 18);
#pragma unroll
  for (int mt = 0; mt < 4; ++mt)
#pragma unroll
    for (int r = 0; r < 4; ++r) {
      const int irow = i0 + wi + (mt << 4) + (kg << 2) + r;
#pragma unroll
      for (int nt = 0; nt < 4; ++nt)
        cp[(irow << 9) + j0 + wj + (nt << 4) + m16] = f2bf(acc[mt][nt][r]);
    }
}

// ---------------- K2b: LN2 + Wo + gate + residual ----------------
// grid 1024 (8x32 cell tiles), 512 thr (8 waves = 8 channel-groups).
__global__ __launch_bounds__(512, 4) void k2b(
    const float* __restrict__ pair,
    const float* __restrict__ ln2w, const float* __restrict__ ln2b,
    const uint16_t* __restrict__ Wc,
    const uint16_t* __restrict__ tri,
    const uint16_t* __restrict__ gbuf2, float* __restrict__ out) {
  __shared__ __align__(16) char smem_[256 * 136 * 2];  // y_s; red overlaps (phase1)
  uint16_t(*y_s)[136] = (uint16_t(*)[136])smem_;
  float2* red = (float2*)smem_;  // [8][256]
  __shared__ float2 stat[256];
  __shared__ float wln[128], bln[128];

  const int t = threadIdx.x, bid = blockIdx.x;
  const int i0 = (bid >> 4) << 3;   // 8 i-rows
  const int j0 = (bid & 15) << 5;   // 32 j-cols
  const int w = t >> 6, lane = t & 63;

  if (t < 128) {
    wln[t] = ln2w[t];
    bln[t] = ln2b[t];
  }

  // ---- phase 1: vectorized tri gather + partial stats ----
  const int il = lane >> 3;          // 0..7
  const int jq4 = (lane & 7) << 2;   // 0..28 step 4
  const uint16_t* tp =
      tri + ((size_t)(w << 4) << 18) + ((i0 + il) << 9) + j0 + jq4;
  ushort4 v4[16];
  float s1[4] = {0.f, 0.f, 0.f, 0.f}, s2[4] = {0.f, 0.f, 0.f, 0.f};
#pragma unroll
  for (int cc = 0; cc < 16; ++cc) {
    ushort4 u = *reinterpret_cast<const ushort4*>(tp + ((size_t)cc << 18));
    v4[cc] = u;
#pragma unroll
    for (int e = 0; e < 4; ++e) {
      float f = bf2f(((const uint16_t*)&u)[e]);
      s1[e] += f;
      s2[e] += f * f;
    }
  }
#pragma unroll
  for (int e = 0; e < 4; ++e)
    red[(w << 8) + (il << 5) + jq4 + e] = make_float2(s1[e], s2[e]);
  __syncthreads();
  if (t < 256) {
    float a1 = 0.f, a2 = 0.f;
#pragma unroll
    for (int ww = 0; ww < 8; ++ww) {
      float2 p = red[(ww << 8) + t];
      a1 += p.x;
      a2 += p.y;
    }
    float mu = a1 * (1.f / 128.f);
    float rs = rsqrtf(a2 * (1.f / 128.f) - mu * mu + 1e-5f);
    stat[t] = make_float2(mu, rs);
  }
  __syncthreads();  // red reads done; safe to overwrite region with y_s

  // ---- phase 2: LN -> y_s bf16 ----
#pragma unroll
  for (int e = 0; e < 4; ++e) {
    const int cell = (il << 5) + jq4 + e;
    const float2 st = stat[cell];
#pragma unroll
    for (int c4 = 0; c4 < 4; ++c4) {
      ushort4 pk;
#pragma unroll
      for (int d = 0; d < 4; ++d) {
        const int c = (w << 4) + (c4 << 2) + d;
        float y =
            (bf2f(((const uint16_t*)&v4[(c4 << 2) + d])[e]) - st.x) * st.y * wln[c] +
            bln[c];
        ((uint16_t*)&pk)[d] = f2bf(y);
      }
      *reinterpret_cast<ushort4*>(&y_s[cell][(w << 4) + (c4 << 2)]) = pk;
    }
  }
  __syncthreads();

  // ---- phase 3: Wo GEMM + gate + residual ----
  const int m16 = lane & 15, kg = lane >> 4;
  const uint16_t* WoC = Wc + (640 << 7);
  bf16x8v af[2][4];
#pragma unroll
  for (int h = 0; h < 2; ++h) {
    const int mt = w + (h << 3);
#pragma unroll
    for (int ks = 0; ks < 4; ++ks)
      af[h][ks] = *reinterpret_cast<const bf16x8v*>(
          &y_s[(mt << 4) + m16][(ks << 5) + (kg << 3)]);
  }

  const f32x4 fz = {0.f, 0.f, 0.f, 0.f};
#pragma unroll
  for (int nt = 0; nt < 8; ++nt) {
    bf16x8v bw[4];
#pragma unroll
    for (int ks = 0; ks < 4; ++ks)
      bw[ks] = ldbf8(WoC + (((nt << 4) + m16) << 7) + (ks << 5) + (kg << 3));
    f32x4 acc0 = fz, acc1 = fz;
#pragma unroll
    for (int ks = 0; ks < 4; ++ks) {
      acc0 = MFMA16(af[0][ks], bw[ks], acc0);
      acc1 = MFMA16(af[1][ks], bw[ks], acc1);
    }
    const int o = (nt << 4) + m16;
#pragma unroll
    for (int h = 0; h < 2; ++h) {
      const int mt = w + (h << 3);
      f32x4 A = h ? acc1 : acc0;
      const int cellb = (mt << 4) + (kg << 2);
      const int i = i0 + (cellb >> 5);
      const int jb = j0 + (cellb & 31);
      ushort4 g4 = *reinterpret_cast<const ushort4*>(
          &gbuf2[(((i << 7) + o) << 9) + jb]);
#pragma unroll
      for (int r = 0; r < 4; ++r) {
        const int off = (((i << 9) + jb + r) << 7) + o;
        out[off] = pair[off] + A[r] * bf2f(((const uint16_t*)&g4)[r]);
      }
    }
  }
}

// ---------------- fallback fused K2 (ws too small) ----------------
__global__ __launch_bounds__(512) void k2(
    const float* __restrict__ pair,
    const float* __restrict__ ln2w, const float* __restrict__ ln2b,
    const uint16_t* __restrict__ Wc,
    const uint16_t* __restrict__ a_t, const uint16_t* __restrict__ b_t,
    const uint16_t* __restrict__ gbuf2, float* __restrict__ out) {
  __shared__ uint16_t y_s[128 * 136];
  __shared__ float2 stat[256];
  float2* red = reinterpret_cast<float2*>(y_s);

  const int bidx = blockIdx.x;
  const int nb = ((bidx & 7) << 7) + (bidx >> 3);
  const int i0 = (nb >> 5) << 4;
  const int j0 = (nb & 31) << 4;
  const int t = threadIdx.x, w = t >> 6, lane = t & 63;
  const int m16 = lane & 15, kg = lane >> 4;
  const int cbase = w << 4;

  const uint16_t* ap = a_t + ((((i0 + m16) << 7) + cbase) << 9) + (kg << 3);
  const uint16_t* bp = b_t + ((((j0 + m16) << 7) + cbase) << 9) + (kg << 3);

  const f32x4 fzero = {0.f, 0.f, 0.f, 0.f};
  f32x4 acc[16];
#pragma unroll
  for (int c = 0; c < 16; ++c) acc[c] = fzero;

  for (int k = 0; k < 512; k += 32) {
#pragma unroll
    for (int c = 0; c < 16; ++c) {
      bf16x8v A = ldbf8(ap + (c << 9) + k);
      bf16x8v B = ldbf8(bp + (c << 9) + k);
      acc[c] = MFMA16(A, B, acc[c]);
    }
  }

  {
    float s1[4] = {0.f, 0.f, 0.f, 0.f};
    float s2[4] = {0.f, 0.f, 0.f, 0.f};
#pragma unroll
    for (int c = 0; c < 16; ++c)
#pragma unroll
      for (int r = 0; r < 4; ++r) {
        float xv = acc[c][r];
        s1[r] += xv;
        s2[r] += xv * xv;
      }
#pragma unroll
    for (int r = 0; r < 4; ++r) {
      int cell = ((kg << 2) + r) * 16 + m16;
      red[(w << 8) + cell] = make_float2(s1[r], s2[r]);
    }
  }
  __syncthreads();
  if (t < 256) {
    float a1 = 0.f, a2 = 0.f;
#pragma unroll
    for (int ww = 0; ww < 8; ++ww) {
      float2 p = red[(ww << 8) + t];
      a1 += p.x;
      a2 += p.y;
    }
    float mu = a1 * (1.f / 128.f);
    float rs = rsqrtf(a2 * (1.f / 128.f) - mu * mu + 1e-5f);
    stat[t] = make_float2(mu, rs);
  }
  __syncthreads();

  const uint16_t* WoC = Wc + (640 << 7);

  for (int half = 0; half < 2; ++half) {
    if ((kg >> 1) == half) {
#pragma unroll
      for (int r = 0; r < 4; ++r) {
        const int iOff = (kg << 2) + r;
        const int cellL = ((iOff - (half << 3)) << 4) + m16;
        const float2 st = stat[(iOff << 4) + m16];
#pragma unroll
        for (int jq = 0; jq < 4; ++jq) {
          ushort4 pk;
#pragma unroll
          for (int e = 0; e < 4; ++e) {
            const int c = (jq << 2) + e;
            float y = (acc[c][r] - st.x) * st.y * ln2w[cbase + c] + ln2b[cbase + c];
            ((uint16_t*)&pk)[e] = f2bf(y);
          }
          *reinterpret_cast<ushort4*>(&y_s[cellL * 136 + cbase + (jq << 2)]) = pk;
        }
      }
    }
    __syncthreads();

    const int mt = (half << 3) + w;
    bf16x8v af2[4];
#pragma unroll
    for (int ks = 0; ks < 4; ++ks)
      af2[ks] = *reinterpret_cast<const bf16x8v*>(
          &y_s[(((mt - (half << 3)) << 4) + m16) * 136 + ks * 32 + (kg << 3)]);
    const int i = i0 + mt;
#pragma unroll
    for (int nt = 0; nt < 8; ++nt) {
      f32x4 a2 = fzero;
#pragma unroll
      for (int ks = 0; ks < 4; ++ks) {
        bf16x8v bw = ldbf8(WoC + (((nt << 4) + m16) << 7) + ks * 32 + (kg << 3));
        a2 = MFMA16(af2[ks], bw, a2);
      }
      const int o = (nt << 4) + m16;
#pragma unroll
      for (int r = 0; r < 4; ++r) {
        const int j = j0 + (kg << 2) + r;
        const int off = (((i << 9) + j) << 7) + o;
        out[off] = pair[off] + a2[r] * bf2f(gbuf2[(((i << 7) + o) << 9) + j]);
      }
    }
    __syncthreads();
  }
}

extern "C" void kernel_launch(void* const* d_in, const int* in_sizes, int n_in,
                              void* d_out, int out_size, void* d_ws, size_t ws_size,
                              hipStream_t stream) {
  const float* pair = (const float*)d_in[0];
  const float* mask = (const float*)d_in[1];
  const float* ln1w = (const float*)d_in[2];
  const float* ln1b = (const float*)d_in[3];
  const float* Wp = (const float*)d_in[4];
  const float* Wg = (const float*)d_in[5];
  const float* ln2w = (const float*)d_in[6];
  const float* ln2b = (const float*)d_in[7];
  const float* Wo = (const float*)d_in[8];
  const float* Wgl = (const float*)d_in[9];

  uint8_t* ws = (uint8_t*)d_ws;
  // layout: Wc 256KB | a_t 64MB | b_t 64MB | gbuf2 64MB | tri 64MB
  uint16_t* Wc = (uint16_t*)(ws);
  uint16_t* a_t = (uint16_t*)(ws + (1 << 18));
  uint16_t* b_t = (uint16_t*)(ws + (1 << 18) + (1ull << 26));
  uint16_t* gb = (uint16_t*)(ws + (1 << 18) + (2ull << 26));
  uint16_t* tri = (uint16_t*)(ws + (1 << 18) + (3ull << 26));
  const size_t NEED = (1 << 18) + (4ull << 26);

  hipLaunchKernelGGL(k_pack, dim3(768), dim3(128), 0, stream, Wp, Wg, Wgl, Wo, Wc);
  hipLaunchKernelGGL(k1, dim3(8192), dim3(256), 0, stream, pair, mask, ln1w, ln1b,
                     Wc, a_t, b_t, gb);
  if (ws_size >= NEED) {
    hipLaunchKernelGGL(k2a, dim3(2048), dim3(256), 0, stream, a_t, b_t, tri);
    hipLaunchKernelGGL(k2b, dim3(1024), dim3(512), 0, stream, pair, ln2w, ln2b,
                       Wc, tri, gb, (float*)d_out);
  } else {
    hipLaunchKernelGGL(k2, dim3(1024), dim3(512), 0, stream, pair, ln2w, ln2b, Wc,
                       a_t, b_t, gb, (float*)d_out);
  }
}